// Round 5
// baseline (422.474 us; speedup 1.0000x reference)
//
#include <hip/hip_runtime.h>
#include <hip/hip_bf16.h>
#include <stdint.h>

#define NN 8192
#define IN_DIM 343
#define IN_PAD 352
#define HID 1000
#define HID_PAD 1024
#define EPS 1e-5f
#define KH 4096           // split-K half length
#define BK2 64            // GEMM2 K-step

typedef __attribute__((ext_vector_type(8))) short bf16x8;
typedef __attribute__((ext_vector_type(4))) float f32x4;

static __device__ __forceinline__ unsigned short f2bf(float f) {
    union { float f; unsigned int u; } v; v.f = f;
    unsigned int u = v.u;
    unsigned int r = (u + 0x7FFFu + ((u >> 16) & 1u)) >> 16;   // RNE
    return (unsigned short)r;
}

static __device__ __forceinline__ unsigned cvt_pk_bf16(float lo, float hi) {
    unsigned r;
    asm("v_cvt_pk_bf16_f32 %0, %1, %2" : "=v"(r) : "v"(lo), "v"(hi));
    return r;
}

// ---------------- conversion kernels ----------------

__global__ __launch_bounds__(256) void k_cvt_feat(const float* __restrict__ src,
                                                  unsigned short* __restrict__ dst) {
    int idx = blockIdx.x * blockDim.x + threadIdx.x;
    if (idx >= NN * IN_PAD) return;
    int row = idx / IN_PAD;
    int col = idx - row * IN_PAD;
    dst[idx] = (col < IN_DIM) ? f2bf(src[(size_t)row * IN_DIM + col]) : 0;
}

__global__ __launch_bounds__(256) void k_cvt_w1t(const float* __restrict__ W1,
                                                 unsigned short* __restrict__ dst) {
    int idx = blockIdx.x * blockDim.x + threadIdx.x;
    if (idx >= HID_PAD * IN_PAD) return;
    int n = idx / IN_PAD;
    int k = idx - n * IN_PAD;
    dst[idx] = (k < IN_DIM && n < HID) ? f2bf(W1[(size_t)k * HID + n]) : 0;
}

// ---------------- GEMM1: bf16 128x128 tile (m97 2-barrier structure) ----------------

__global__ void k_gemm_bf(const unsigned short* __restrict__ A,
                          const unsigned short* __restrict__ Bt,
                          unsigned short* __restrict__ Cout,
                          int M, int N, int K) {
    __shared__ unsigned short ldsA[128 * 32];
    __shared__ unsigned short ldsB[128 * 32];

    const int tid = threadIdx.x;
    const int nbn = N >> 7;
    const int bm = blockIdx.x / nbn;
    const int bn = blockIdx.x - bm * nbn;

    const int wid = tid >> 6, lane = tid & 63;
    const int wr = wid >> 1, wc = wid & 1;
    const int lr = lane & 15, lg = lane >> 4;

    f32x4 acc[4][4] = {};

    const int r0 = tid >> 2, s0 = tid & 3;
    const unsigned short* Ag0 = A + ((size_t)bm * 128 + r0) * K + s0 * 8;
    const unsigned short* Ag1 = A + ((size_t)bm * 128 + 64 + r0) * K + s0 * 8;
    const unsigned short* Bg0 = Bt + ((size_t)bn * 128 + r0) * K + s0 * 8;
    const unsigned short* Bg1 = Bt + ((size_t)bn * 128 + 64 + r0) * K + s0 * 8;
    unsigned short* lA0 = ldsA + (size_t)(wid * 64) * 8;
    unsigned short* lA1 = ldsA + (size_t)(256 + wid * 64) * 8;
    unsigned short* lB0 = ldsB + (size_t)(wid * 64) * 8;
    unsigned short* lB1 = ldsB + (size_t)(256 + wid * 64) * 8;

    for (int kt = 0; kt < K; kt += 32) {
        __builtin_amdgcn_global_load_lds(
            (const __attribute__((address_space(1))) void*)(Ag0 + kt),
            (__attribute__((address_space(3))) void*)lA0, 16, 0, 0);
        __builtin_amdgcn_global_load_lds(
            (const __attribute__((address_space(1))) void*)(Ag1 + kt),
            (__attribute__((address_space(3))) void*)lA1, 16, 0, 0);
        __builtin_amdgcn_global_load_lds(
            (const __attribute__((address_space(1))) void*)(Bg0 + kt),
            (__attribute__((address_space(3))) void*)lB0, 16, 0, 0);
        __builtin_amdgcn_global_load_lds(
            (const __attribute__((address_space(1))) void*)(Bg1 + kt),
            (__attribute__((address_space(3))) void*)lB1, 16, 0, 0);
        __syncthreads();

        bf16x8 af[4], bfr[4];
#pragma unroll
        for (int i = 0; i < 4; i++) {
            af[i]  = *(const bf16x8*)&ldsA[((wr * 64 + i * 16 + lr) * 32) + lg * 8];
            bfr[i] = *(const bf16x8*)&ldsB[((wc * 64 + i * 16 + lr) * 32) + lg * 8];
        }
#pragma unroll
        for (int i = 0; i < 4; i++)
#pragma unroll
            for (int j = 0; j < 4; j++)
                acc[i][j] = __builtin_amdgcn_mfma_f32_16x16x32_bf16(af[i], bfr[j], acc[i][j], 0, 0, 0);
        __syncthreads();
    }

    const int row0 = bm * 128 + wr * 64;
    const int col0 = bn * 128 + wc * 64;
#pragma unroll
    for (int mi = 0; mi < 4; mi++) {
#pragma unroll
        for (int ni = 0; ni < 4; ni++) {
            int col = col0 + ni * 16 + lr;
#pragma unroll
            for (int j = 0; j < 4; j++) {
                int row = row0 + mi * 16 + lg * 4 + j;
                Cout[(size_t)row * N + col] = f2bf(acc[mi][ni][j]);
            }
        }
    }
}

// ---------------- GEMM2: adj(fp32, staged raw via global_load_lds) * xwt^T ----------------
// m97 2-barrier structure, BK=64, split-K=2, XCD swizzle. fp32->bf16 conversion happens
// at fragment-build: 2x ds_read_b128 fp32 + 4x v_cvt_pk_bf16_f32 per A-fragment.
// No register round-trip for staging; all staging is async global_load_lds.

__global__ __launch_bounds__(256) void k_gemm2(const float* __restrict__ A,
                                               const unsigned short* __restrict__ Bt,
                                               float* __restrict__ Cpart) {
    __shared__ float          ldsAf[128 * BK2];     // 32 KB (fp32 A tile)
    __shared__ unsigned short ldsBh[128 * BK2];     // 16 KB (bf16 B tile)

    const int tid = threadIdx.x;
    const int wg = blockIdx.x;
    const int swz = (wg & 7) * 128 + (wg >> 3);     // bijective, 1024 = 8*128
    const int bm = swz >> 4;          // 0..63
    const int rem = swz & 15;
    const int ks = rem >> 3;          // 0..1
    const int bn = rem & 7;           // 0..7
    const size_t k0 = (size_t)ks * KH;

    const int wid = tid >> 6, lane = tid & 63;
    const int wr = wid >> 1, wc = wid & 1;
    const int lr = lane & 15, lg = lane >> 4;

    f32x4 acc[4][4] = {};

    // A staging: 32 chunks of 1KB (4 rows x 256B); wave w issues chunks w*8..w*8+7.
    const int ar4  = lane >> 4;       // row within chunk (0..3)
    const int as16 = lane & 15;       // 16B slot within row (0..15)
    // B staging: 16 chunks of 1KB (8 rows x 128B); wave w issues chunks w*4..w*4+3.
    const int br8 = lane >> 3;        // row within chunk (0..7)
    const int bs8 = lane & 7;         // 16B slot within row (0..7)

    const float* Abase = A + ((size_t)bm * 128) * NN + k0;
    const unsigned short* Bbase = Bt + ((size_t)bn * 128) * NN + k0;

    for (int kt = 0; kt < KH; kt += BK2) {
#pragma unroll
        for (int q = 0; q < 8; q++) {
            const int c = wid * 8 + q;
            __builtin_amdgcn_global_load_lds(
                (const __attribute__((address_space(1))) void*)
                    (Abase + (size_t)(c * 4 + ar4) * NN + kt + as16 * 4),
                (__attribute__((address_space(3))) void*)(ldsAf + c * 256),
                16, 0, 0);
        }
#pragma unroll
        for (int q = 0; q < 4; q++) {
            const int c = wid * 4 + q;
            __builtin_amdgcn_global_load_lds(
                (const __attribute__((address_space(1))) void*)
                    (Bbase + (size_t)(c * 8 + br8) * NN + kt + bs8 * 8),
                (__attribute__((address_space(3))) void*)(ldsBh + c * 512),
                16, 0, 0);
        }
        __syncthreads();

#pragma unroll
        for (int kk = 0; kk < 2; kk++) {
            bf16x8 af[4], bfr[4];
#pragma unroll
            for (int i = 0; i < 4; i++) {
                const int row = wr * 64 + i * 16 + lr;
                const f32x4 lo = *(const f32x4*)&ldsAf[row * 64 + kk * 32 + lg * 8];
                const f32x4 hi = *(const f32x4*)&ldsAf[row * 64 + kk * 32 + lg * 8 + 4];
                union { uint32_t u[4]; bf16x8 v; } pk;
                pk.u[0] = cvt_pk_bf16(lo[0], lo[1]);
                pk.u[1] = cvt_pk_bf16(lo[2], lo[3]);
                pk.u[2] = cvt_pk_bf16(hi[0], hi[1]);
                pk.u[3] = cvt_pk_bf16(hi[2], hi[3]);
                af[i] = pk.v;
            }
#pragma unroll
            for (int j = 0; j < 4; j++) {
                const int row = wc * 64 + j * 16 + lr;
                bfr[j] = *(const bf16x8*)&ldsBh[row * 64 + kk * 32 + lg * 8];
            }
#pragma unroll
            for (int i = 0; i < 4; i++)
#pragma unroll
                for (int j = 0; j < 4; j++)
                    acc[i][j] = __builtin_amdgcn_mfma_f32_16x16x32_bf16(af[i], bfr[j], acc[i][j], 0, 0, 0);
        }
        __syncthreads();
    }

    float* Cout = Cpart + (size_t)ks * NN * HID_PAD;
    const int row0 = bm * 128 + wr * 64;
    const int col0 = bn * 128 + wc * 64;
#pragma unroll
    for (int mi = 0; mi < 4; mi++) {
#pragma unroll
        for (int ni = 0; ni < 4; ni++) {
            int col = col0 + ni * 16 + lr;
#pragma unroll
            for (int j = 0; j < 4; j++) {
                int row = row0 + mi * 16 + lg * 4 + j;
                Cout[(size_t)row * HID_PAD + col] = acc[mi][ni][j];
            }
        }
    }
}

// ---------------- LayerNorm + head; fuses split-K reduce + bias + relu ----------------
__global__ __launch_bounds__(256) void k_ln_head(const float* __restrict__ p0,
                                                 const float* __restrict__ p1,
                                                 const float* __restrict__ b1,
                                                 const float* __restrict__ gamma,
                                                 const float* __restrict__ beta,
                                                 const float* __restrict__ Wm,
                                                 const float* __restrict__ bm,
                                                 float* __restrict__ out) {
    const int row = blockIdx.x;
    const int t = threadIdx.x;
    const float* h0 = p0 + (size_t)row * HID_PAD;
    const float* h1 = p1 + (size_t)row * HID_PAD;

    float v[4];
    float s = 0.f, ss = 0.f;
#pragma unroll
    for (int i = 0; i < 4; i++) {
        int ix = t + i * 256;
        float x = 0.f;
        if (ix < HID) {
            x = h0[ix] + h1[ix] + b1[ix];
            x = x > 0.f ? x : 0.f;
        }
        v[i] = x; s += x; ss += x * x;
    }
#pragma unroll
    for (int o = 32; o > 0; o >>= 1) { s += __shfl_down(s, o); ss += __shfl_down(ss, o); }

    __shared__ float rs[8], rss[8];
    const int wid = t >> 6, lane = t & 63;
    if (lane == 0) { rs[wid] = s; rss[wid] = ss; }
    __syncthreads();
    if (t == 0) {
        float a = 0.f, b = 0.f;
        for (int w = 0; w < 4; w++) { a += rs[w]; b += rss[w]; }
        rs[4] = a; rss[4] = b;
    }
    __syncthreads();
    const float mean = rs[4] * (1.0f / HID);
    const float var = rss[4] * (1.0f / HID) - mean * mean;
    const float rstd = rsqrtf(var + EPS);

    float q0 = 0.f, q1 = 0.f, q2 = 0.f, q3 = 0.f;
#pragma unroll
    for (int i = 0; i < 4; i++) {
        int ix = t + i * 256;
        if (ix < HID) {
            float hn = (v[i] - mean) * rstd * gamma[ix] + beta[ix];
            const float* w = Wm + (size_t)ix * 4;
            q0 += hn * w[0]; q1 += hn * w[1]; q2 += hn * w[2]; q3 += hn * w[3];
        }
    }
#pragma unroll
    for (int o = 32; o > 0; o >>= 1) {
        q0 += __shfl_down(q0, o); q1 += __shfl_down(q1, o);
        q2 += __shfl_down(q2, o); q3 += __shfl_down(q3, o);
    }
    __shared__ float rp[4][4];
    if (lane == 0) { rp[wid][0] = q0; rp[wid][1] = q1; rp[wid][2] = q2; rp[wid][3] = q3; }
    __syncthreads();
    if (t < 4) {
        float a = rp[0][t] + rp[1][t] + rp[2][t] + rp[3][t] + bm[t];
        out[(size_t)row * 4 + t] = a;
    }
}

// ---------------- launcher ----------------
extern "C" void kernel_launch(void* const* d_in, const int* in_sizes, int n_in,
                              void* d_out, int out_size, void* d_ws, size_t ws_size,
                              hipStream_t stream) {
    const float* adj      = (const float*)d_in[0];
    const float* features = (const float*)d_in[1];
    const float* W1       = (const float*)d_in[2];
    const float* b1       = (const float*)d_in[3];
    const float* gamma    = (const float*)d_in[4];
    const float* beta     = (const float*)d_in[5];
    const float* Wm       = (const float*)d_in[6];
    const float* bm       = (const float*)d_in[7];
    float* out = (float*)d_out;

    uint8_t* ws = (uint8_t*)d_ws;
    unsigned short* feat_p = (unsigned short*)ws;                 //  5,767,168 B
    unsigned short* w1t    = (unsigned short*)(ws + 5767168);     //    720,896 B
    unsigned short* xwt    = (unsigned short*)(ws + 6488064);     // 16,777,216 B
    float*          part0  = (float*)(ws + 23265280);             // 33,554,432 B
    float*          part1  = (float*)(ws + 56819712);             // 33,554,432 B (contiguous)

    k_cvt_feat<<<(NN * IN_PAD + 255) / 256, 256, 0, stream>>>(features, feat_p);
    k_cvt_w1t<<<(HID_PAD * IN_PAD + 255) / 256, 256, 0, stream>>>(W1, w1t);

    k_gemm_bf<<<(HID_PAD / 128) * (NN / 128), 256, 0, stream>>>(
        w1t, feat_p, xwt, HID_PAD, NN, IN_PAD);

    k_gemm2<<<1024, 256, 0, stream>>>(adj, xwt, part0);   // ks=1 half lands in part1

    k_ln_head<<<NN, 256, 0, stream>>>(part0, part1, b1, gamma, beta, Wm, bm, out);
}

// Round 6
// 302.419 us; speedup vs baseline: 1.3970x; 1.3970x over previous
//
#include <hip/hip_runtime.h>
#include <hip/hip_bf16.h>
#include <stdint.h>

#define NN 8192
#define IN_DIM 343
#define IN_PAD 352
#define HID 1000
#define HID_PAD 1024
#define EPS 1e-5f
#define KH 4096           // split-K half length
#define BK2 32            // GEMM2 K-step

typedef __attribute__((ext_vector_type(8))) short bf16x8;
typedef __attribute__((ext_vector_type(4))) float f32x4;

static __device__ __forceinline__ unsigned short f2bf(float f) {
    union { float f; unsigned int u; } v; v.f = f;
    unsigned int u = v.u;
    unsigned int r = (u + 0x7FFFu + ((u >> 16) & 1u)) >> 16;   // RNE
    return (unsigned short)r;
}

static __device__ __forceinline__ unsigned cvt_pk_bf16(float lo, float hi) {
    unsigned r;
    asm("v_cvt_pk_bf16_f32 %0, %1, %2" : "=v"(r) : "v"(lo), "v"(hi));
    return r;
}

// ---------------- conversion kernels ----------------

__global__ __launch_bounds__(256) void k_cvt_feat(const float* __restrict__ src,
                                                  unsigned short* __restrict__ dst) {
    int idx = blockIdx.x * blockDim.x + threadIdx.x;
    if (idx >= NN * IN_PAD) return;
    int row = idx / IN_PAD;
    int col = idx - row * IN_PAD;
    dst[idx] = (col < IN_DIM) ? f2bf(src[(size_t)row * IN_DIM + col]) : 0;
}

__global__ __launch_bounds__(256) void k_cvt_w1t(const float* __restrict__ W1,
                                                 unsigned short* __restrict__ dst) {
    int idx = blockIdx.x * blockDim.x + threadIdx.x;
    if (idx >= HID_PAD * IN_PAD) return;
    int n = idx / IN_PAD;
    int k = idx - n * IN_PAD;
    dst[idx] = (k < IN_DIM && n < HID) ? f2bf(W1[(size_t)k * HID + n]) : 0;
}

// ---------------- GEMM1: bf16 128x128 tile (m97 2-barrier structure) ----------------

__global__ void k_gemm_bf(const unsigned short* __restrict__ A,
                          const unsigned short* __restrict__ Bt,
                          unsigned short* __restrict__ Cout,
                          int M, int N, int K) {
    __shared__ unsigned short ldsA[128 * 32];
    __shared__ unsigned short ldsB[128 * 32];

    const int tid = threadIdx.x;
    const int nbn = N >> 7;
    const int bm = blockIdx.x / nbn;
    const int bn = blockIdx.x - bm * nbn;

    const int wid = tid >> 6, lane = tid & 63;
    const int wr = wid >> 1, wc = wid & 1;
    const int lr = lane & 15, lg = lane >> 4;

    f32x4 acc[4][4] = {};

    const int r0 = tid >> 2, s0 = tid & 3;
    const unsigned short* Ag0 = A + ((size_t)bm * 128 + r0) * K + s0 * 8;
    const unsigned short* Ag1 = A + ((size_t)bm * 128 + 64 + r0) * K + s0 * 8;
    const unsigned short* Bg0 = Bt + ((size_t)bn * 128 + r0) * K + s0 * 8;
    const unsigned short* Bg1 = Bt + ((size_t)bn * 128 + 64 + r0) * K + s0 * 8;
    unsigned short* lA0 = ldsA + (size_t)(wid * 64) * 8;
    unsigned short* lA1 = ldsA + (size_t)(256 + wid * 64) * 8;
    unsigned short* lB0 = ldsB + (size_t)(wid * 64) * 8;
    unsigned short* lB1 = ldsB + (size_t)(256 + wid * 64) * 8;

    for (int kt = 0; kt < K; kt += 32) {
        __builtin_amdgcn_global_load_lds(
            (const __attribute__((address_space(1))) void*)(Ag0 + kt),
            (__attribute__((address_space(3))) void*)lA0, 16, 0, 0);
        __builtin_amdgcn_global_load_lds(
            (const __attribute__((address_space(1))) void*)(Ag1 + kt),
            (__attribute__((address_space(3))) void*)lA1, 16, 0, 0);
        __builtin_amdgcn_global_load_lds(
            (const __attribute__((address_space(1))) void*)(Bg0 + kt),
            (__attribute__((address_space(3))) void*)lB0, 16, 0, 0);
        __builtin_amdgcn_global_load_lds(
            (const __attribute__((address_space(1))) void*)(Bg1 + kt),
            (__attribute__((address_space(3))) void*)lB1, 16, 0, 0);
        __syncthreads();

        bf16x8 af[4], bfr[4];
#pragma unroll
        for (int i = 0; i < 4; i++) {
            af[i]  = *(const bf16x8*)&ldsA[((wr * 64 + i * 16 + lr) * 32) + lg * 8];
            bfr[i] = *(const bf16x8*)&ldsB[((wc * 64 + i * 16 + lr) * 32) + lg * 8];
        }
#pragma unroll
        for (int i = 0; i < 4; i++)
#pragma unroll
            for (int j = 0; j < 4; j++)
                acc[i][j] = __builtin_amdgcn_mfma_f32_16x16x32_bf16(af[i], bfr[j], acc[i][j], 0, 0, 0);
        __syncthreads();
    }

    const int row0 = bm * 128 + wr * 64;
    const int col0 = bn * 128 + wc * 64;
#pragma unroll
    for (int mi = 0; mi < 4; mi++) {
#pragma unroll
        for (int ni = 0; ni < 4; ni++) {
            int col = col0 + ni * 16 + lr;
#pragma unroll
            for (int j = 0; j < 4; j++) {
                int row = row0 + mi * 16 + lg * 4 + j;
                Cout[(size_t)row * N + col] = f2bf(acc[mi][ni][j]);
            }
        }
    }
}

// ---------------- GEMM2: adj fp32 staged via global_load_lds, XOR-swizzled LDS ----------------
// BK=32, split-K=2, XCD swizzle, m97 2-barrier structure. Swizzle (rule #21): LDS dest
// stays linear; the GLOBAL source col-slot is pre-permuted per lane, and reads apply the
// same involution. A: slot' = slot ^ (row&7) (8x16B slots). B: slot' = slot ^ ((row>>1)&3)
// (4x16B slots; row stride 64B only spans 16 banks, so parity+slot must jointly spread).

__global__ __launch_bounds__(256, 3) void k_gemm2(const float* __restrict__ A,
                                                  const unsigned short* __restrict__ Bt,
                                                  float* __restrict__ Cpart) {
    __shared__ float          ldsAf[128 * BK2];     // 16 KB
    __shared__ unsigned short ldsBh[128 * BK2];     //  8 KB

    const int tid = threadIdx.x;
    const int wg = blockIdx.x;
    const int swz = (wg & 7) * 128 + (wg >> 3);     // bijective, 1024 = 8*128
    const int bm = swz >> 4;          // 0..63
    const int rem = swz & 15;
    const int ks = rem >> 3;          // 0..1
    const int bn = rem & 7;           // 0..7
    const size_t k0 = (size_t)ks * KH;

    const int wid = tid >> 6, lane = tid & 63;
    const int wr = wid >> 1, wc = wid & 1;
    const int lr = lane & 15, lg = lane >> 4;

    f32x4 acc[4][4] = {};

    const float* Abase = A + ((size_t)bm * 128) * NN + k0;
    const unsigned short* Bbase = Bt + ((size_t)bn * 128) * NN + k0;

    // staging source col-slots (pre-swizzled so linear LDS ends up XOR-swizzled)
    const int aslot = (lane & 7) ^ (lane >> 3);            // A: row-in-instr = lane>>3 = r&7
    const int bslot = (lane & 3) ^ ((lane >> 3) & 3);      // B: (r>>1)&3 = (lane>>3)&3

    for (int kt = 0; kt < KH; kt += BK2) {
        // A: 4 instrs x 1KB; rows q*32 + wid*8 + (lane>>3)
#pragma unroll
        for (int q = 0; q < 4; q++) {
            const int r = q * 32 + wid * 8 + (lane >> 3);
            __builtin_amdgcn_global_load_lds(
                (const __attribute__((address_space(1))) void*)
                    (Abase + (size_t)r * NN + kt + aslot * 4),
                (__attribute__((address_space(3))) void*)(ldsAf + q * 1024 + wid * 256),
                16, 0, 0);
        }
        // B: 2 instrs x 1KB; rows q*64 + wid*16 + (lane>>2)
#pragma unroll
        for (int q = 0; q < 2; q++) {
            const int r = q * 64 + wid * 16 + (lane >> 2);
            __builtin_amdgcn_global_load_lds(
                (const __attribute__((address_space(1))) void*)
                    (Bbase + (size_t)r * NN + kt + bslot * 8),
                (__attribute__((address_space(3))) void*)(ldsBh + q * 2048 + wid * 512),
                16, 0, 0);
        }
        __syncthreads();

        bf16x8 af[4], bfr[4];
#pragma unroll
        for (int i = 0; i < 4; i++) {
            const int r = wr * 64 + i * 16 + lr;          // r&7 == lr&7
            const int p0 = (lg * 2)     ^ (lr & 7);
            const int p1 = (lg * 2 + 1) ^ (lr & 7);
            const f32x4 lo = *(const f32x4*)&ldsAf[r * 32 + p0 * 4];
            const f32x4 hi = *(const f32x4*)&ldsAf[r * 32 + p1 * 4];
            union { uint32_t u[4]; bf16x8 v; } pk;
            pk.u[0] = cvt_pk_bf16(lo[0], lo[1]);
            pk.u[1] = cvt_pk_bf16(lo[2], lo[3]);
            pk.u[2] = cvt_pk_bf16(hi[0], hi[1]);
            pk.u[3] = cvt_pk_bf16(hi[2], hi[3]);
            af[i] = pk.v;
        }
#pragma unroll
        for (int j = 0; j < 4; j++) {
            const int r = wc * 64 + j * 16 + lr;          // (r>>1)&3 == (lr>>1)&3
            const int p = lg ^ ((lr >> 1) & 3);
            bfr[j] = *(const bf16x8*)&ldsBh[r * 32 + p * 8];
        }
#pragma unroll
        for (int i = 0; i < 4; i++)
#pragma unroll
            for (int j = 0; j < 4; j++)
                acc[i][j] = __builtin_amdgcn_mfma_f32_16x16x32_bf16(af[i], bfr[j], acc[i][j], 0, 0, 0);
        __syncthreads();
    }

    float* Cout = Cpart + (size_t)ks * NN * HID_PAD;
    const int row0 = bm * 128 + wr * 64;
    const int col0 = bn * 128 + wc * 64;
#pragma unroll
    for (int mi = 0; mi < 4; mi++) {
#pragma unroll
        for (int ni = 0; ni < 4; ni++) {
            int col = col0 + ni * 16 + lr;
#pragma unroll
            for (int j = 0; j < 4; j++) {
                int row = row0 + mi * 16 + lg * 4 + j;
                Cout[(size_t)row * HID_PAD + col] = acc[mi][ni][j];
            }
        }
    }
}

// ---------------- LayerNorm + head; fuses split-K reduce + bias + relu ----------------
__global__ __launch_bounds__(256) void k_ln_head(const float* __restrict__ p0,
                                                 const float* __restrict__ p1,
                                                 const float* __restrict__ b1,
                                                 const float* __restrict__ gamma,
                                                 const float* __restrict__ beta,
                                                 const float* __restrict__ Wm,
                                                 const float* __restrict__ bm,
                                                 float* __restrict__ out) {
    const int row = blockIdx.x;
    const int t = threadIdx.x;
    const float* h0 = p0 + (size_t)row * HID_PAD;
    const float* h1 = p1 + (size_t)row * HID_PAD;

    float v[4];
    float s = 0.f, ss = 0.f;
#pragma unroll
    for (int i = 0; i < 4; i++) {
        int ix = t + i * 256;
        float x = 0.f;
        if (ix < HID) {
            x = h0[ix] + h1[ix] + b1[ix];
            x = x > 0.f ? x : 0.f;
        }
        v[i] = x; s += x; ss += x * x;
    }
#pragma unroll
    for (int o = 32; o > 0; o >>= 1) { s += __shfl_down(s, o); ss += __shfl_down(ss, o); }

    __shared__ float rs[8], rss[8];
    const int wid = t >> 6, lane = t & 63;
    if (lane == 0) { rs[wid] = s; rss[wid] = ss; }
    __syncthreads();
    if (t == 0) {
        float a = 0.f, b = 0.f;
        for (int w = 0; w < 4; w++) { a += rs[w]; b += rss[w]; }
        rs[4] = a; rss[4] = b;
    }
    __syncthreads();
    const float mean = rs[4] * (1.0f / HID);
    const float var = rss[4] * (1.0f / HID) - mean * mean;
    const float rstd = rsqrtf(var + EPS);

    float q0 = 0.f, q1 = 0.f, q2 = 0.f, q3 = 0.f;
#pragma unroll
    for (int i = 0; i < 4; i++) {
        int ix = t + i * 256;
        if (ix < HID) {
            float hn = (v[i] - mean) * rstd * gamma[ix] + beta[ix];
            const float* w = Wm + (size_t)ix * 4;
            q0 += hn * w[0]; q1 += hn * w[1]; q2 += hn * w[2]; q3 += hn * w[3];
        }
    }
#pragma unroll
    for (int o = 32; o > 0; o >>= 1) {
        q0 += __shfl_down(q0, o); q1 += __shfl_down(q1, o);
        q2 += __shfl_down(q2, o); q3 += __shfl_down(q3, o);
    }
    __shared__ float rp[4][4];
    if (lane == 0) { rp[wid][0] = q0; rp[wid][1] = q1; rp[wid][2] = q2; rp[wid][3] = q3; }
    __syncthreads();
    if (t < 4) {
        float a = rp[0][t] + rp[1][t] + rp[2][t] + rp[3][t] + bm[t];
        out[(size_t)row * 4 + t] = a;
    }
}

// ---------------- launcher ----------------
extern "C" void kernel_launch(void* const* d_in, const int* in_sizes, int n_in,
                              void* d_out, int out_size, void* d_ws, size_t ws_size,
                              hipStream_t stream) {
    const float* adj      = (const float*)d_in[0];
    const float* features = (const float*)d_in[1];
    const float* W1       = (const float*)d_in[2];
    const float* b1       = (const float*)d_in[3];
    const float* gamma    = (const float*)d_in[4];
    const float* beta     = (const float*)d_in[5];
    const float* Wm       = (const float*)d_in[6];
    const float* bm       = (const float*)d_in[7];
    float* out = (float*)d_out;

    uint8_t* ws = (uint8_t*)d_ws;
    unsigned short* feat_p = (unsigned short*)ws;                 //  5,767,168 B
    unsigned short* w1t    = (unsigned short*)(ws + 5767168);     //    720,896 B
    unsigned short* xwt    = (unsigned short*)(ws + 6488064);     // 16,777,216 B
    float*          part0  = (float*)(ws + 23265280);             // 33,554,432 B
    float*          part1  = (float*)(ws + 56819712);             // 33,554,432 B (contiguous)

    k_cvt_feat<<<(NN * IN_PAD + 255) / 256, 256, 0, stream>>>(features, feat_p);
    k_cvt_w1t<<<(HID_PAD * IN_PAD + 255) / 256, 256, 0, stream>>>(W1, w1t);

    k_gemm_bf<<<(HID_PAD / 128) * (NN / 128), 256, 0, stream>>>(
        w1t, feat_p, xwt, HID_PAD, NN, IN_PAD);

    k_gemm2<<<1024, 256, 0, stream>>>(adj, xwt, part0);   // ks=1 half lands in part1

    k_ln_head<<<NN, 256, 0, stream>>>(part0, part1, b1, gamma, beta, Wm, bm, out);
}